// Round 15
// baseline (75.877 us; speedup 1.0000x reference)
//
#include <hip/hip_runtime.h>
#include <math.h>

// LSH attention: B=2, H=8, S=2048, D=64, 6 bits -> 64 buckets, exact-match.
// 3 dispatches:
//  1) lsh_buckets2: bucket codes for Q and K (sign of X.rot)
//  2) lsh_sortfuse_bh: ONE block per bh, K pass then Q pass; Q-list entries
//     carry K-side bucket info inline (e0=q0|ks<<16, e1=q1|nk<<16; 0xFFFF = pad)
//  3) lsh_attn_g: wave per 4 same-bucket queries, low-VGPR body; XCD-pinned
//     1-D grid; block->group-block mapping strided by coprime 37 so each CU
//     gets a mix of heavy/light buckets (tail-balance) while the 4 waves of a
//     block stay on consecutive same-bucket groups (L1/L2 locality).

constexpr int S_LEN = 2048;
constexpr int D = 64;
constexpr int NHASH = 6;
constexpr int BH = 16;     // B*H
constexpr int NB = 64;     // 2^NHASH
constexpr int QPAD = 4;    // queries per wave
constexpr int PADQ = S_LEN + (QPAD - 1) * NB;   // 2240
constexpr int NGRP = PADQ / QPAD;               // 560 wave-groups per bh
constexpr int NBLK = NGRP / 4;                  // 140 blocks per bh (4 waves each)
constexpr int GSTRIDE = 37;                     // coprime with 140: bijective

// ---- Phase 1: bucket codes for Q and K in one dispatch. One wave per vector.
__global__ __launch_bounds__(256) void lsh_buckets2(const float* __restrict__ Q,
                                                    const float* __restrict__ K,
                                                    const float* __restrict__ rot,
                                                    int* __restrict__ qb,
                                                    int* __restrict__ kb) {
    const int gw   = (blockIdx.x * 256 + threadIdx.x) >> 6;
    const int lane = threadIdx.x & 63;
    const bool isK = gw >= BH * S_LEN;
    const int wid  = isK ? gw - BH * S_LEN : gw;
    const float* X = isK ? K : Q;
    int* dst       = isK ? kb : qb;
    const int h    = (wid >> 11) & 7;

    const float x  = X[(size_t)wid * D + lane];
    const float* r = rot + (size_t)h * NHASH * D + lane;
    float p0 = x * r[0 * D], p1 = x * r[1 * D], p2 = x * r[2 * D];
    float p3 = x * r[3 * D], p4 = x * r[4 * D], p5 = x * r[5 * D];
#pragma unroll
    for (int off = 32; off >= 1; off >>= 1) {
        p0 += __shfl_xor(p0, off, 64);
        p1 += __shfl_xor(p1, off, 64);
        p2 += __shfl_xor(p2, off, 64);
        p3 += __shfl_xor(p3, off, 64);
        p4 += __shfl_xor(p4, off, 64);
        p5 += __shfl_xor(p5, off, 64);
    }
    int bucket = (p0 > 0.f ? 1 : 0) | (p1 > 0.f ? 2 : 0) | (p2 > 0.f ? 4 : 0) |
                 (p3 > 0.f ? 8 : 0) | (p4 > 0.f ? 16 : 0) | (p5 > 0.f ? 32 : 0);
    if (lane == 0) dst[wid] = bucket;
}

// ---- Phase 2: fused per-bh sort. One block per bh (16 blocks x 256 threads).
__global__ __launch_bounds__(256) void lsh_sortfuse_bh(const int* __restrict__ qbuckets,
                                                       const int* __restrict__ kbuckets,
                                                       int* __restrict__ q_plist,  // [BH][PADQ]
                                                       int* __restrict__ k_list) { // [BH][S]
    __shared__ int hist[NB];
    __shared__ int cur[NB];
    __shared__ int kst[NB], kcnt[NB];
    __shared__ int qst[NB];
    __shared__ int total;
    const int bh  = blockIdx.x;
    const int tid = threadIdx.x;

    // ================= K pass =================
    if (tid < NB) hist[tid] = 0;
    __syncthreads();
    int myk[8];
#pragma unroll
    for (int i = 0; i < 8; ++i) {
        myk[i] = kbuckets[bh * S_LEN + i * 256 + tid];   // coalesced
        atomicAdd(&hist[myk[i]], 1);
    }
    __syncthreads();
    if (tid < NB) {   // wave 0: shuffle-scan the 64 bucket sizes
        const int cnt = hist[tid];
        int x = cnt;
#pragma unroll
        for (int off = 1; off < 64; off <<= 1) {
            const int y = __shfl_up(x, off, 64);
            if (tid >= off) x += y;
        }
        kst[tid]  = x - cnt;
        kcnt[tid] = cnt;
        cur[tid]  = x - cnt;
    }
    __syncthreads();
    {
        int* klp = k_list + bh * S_LEN;
#pragma unroll
        for (int i = 0; i < 8; ++i) {
            const int b    = myk[i];
            const int slot = atomicAdd(&cur[b], 1);
            klp[slot] = i * 256 + tid;
        }
    }
    __syncthreads();

    // ================= Q pass =================
    if (tid < NB) hist[tid] = 0;
    __syncthreads();
    int myq[8];
#pragma unroll
    for (int i = 0; i < 8; ++i) {
        myq[i] = qbuckets[bh * S_LEN + i * 256 + tid];
        atomicAdd(&hist[myq[i]], 1);
    }
    __syncthreads();
    if (tid < NB) {
        const int cnt = hist[tid];
        const int v   = (cnt + QPAD - 1) & ~(QPAD - 1);
        int x = v;
#pragma unroll
        for (int off = 1; off < 64; off <<= 1) {
            const int y = __shfl_up(x, off, 64);
            if (tid >= off) x += y;
        }
        qst[tid] = x - v;
        cur[tid] = x - v;
        if (tid == 63) total = x;
    }
    __syncthreads();

    int* qp = q_plist + bh * PADQ;
    // per-bucket pad sentinels (q-field 0xFFFF; keep nk in high bits for pos1)
    if (tid < NB) {
        const int cnt    = hist[tid];
        const int padded = (cnt + QPAD - 1) & ~(QPAD - 1);
        const int sent   = 0xFFFF | (kcnt[tid] << 16);
        for (int t = qst[tid] + cnt; t < qst[tid] + padded; ++t) qp[t] = sent;
    }
    for (int t = total + tid; t < PADQ; t += 256) qp[t] = -1;   // whole-group sentinel
    // scatter: entry layout depends on slot position within its group
#pragma unroll
    for (int i = 0; i < 8; ++i) {
        const int b    = myq[i];
        const int slot = atomicAdd(&cur[b], 1);
        const int pos  = slot & 3;
        int e = i * 256 + tid;
        if (pos == 0)      e |= kst[b] << 16;
        else if (pos == 1) e |= kcnt[b] << 16;
        qp[slot] = e;
    }
}

// ---- Phase 3: wave per 4 same-bucket queries, low-VGPR body.
// 1-D grid, XCD-pinned: w -> bh=(w&7)+8*((w>>3)&1), blk=w>>4.
// Block blk maps to group-block gb = blk*37 mod 140 (bijective): adjacent
// dispatched blocks sample distant bucket sizes -> per-CU heavy/light mix.
__global__ __launch_bounds__(256) void lsh_attn_g(const float* __restrict__ Q,
                                                  const float* __restrict__ K,
                                                  const float* __restrict__ V,
                                                  const int* __restrict__ q_plist,
                                                  const int* __restrict__ k_list,
                                                  float* __restrict__ out) {
    __shared__ float wbuf[4][QPAD][64];   // [wave][query][key-lane]
    __shared__ int   kbuf[4][64];

    const int wv   = threadIdx.x >> 6;
    const int lane = threadIdx.x & 63;
    const int w    = blockIdx.x;
    const int bh   = (w & 7) + 8 * ((w >> 3) & 1);   // XCD w&7 serves bh, bh+8
    const int gb   = ((w >> 4) * GSTRIDE) % NBLK;    // strided tail-balance
    const int grp  = gb * 4 + wv;                    // 4 consecutive groups/block

    const int* pl = q_plist + bh * PADQ + 4 * grp;
    const int e0 = __builtin_amdgcn_readfirstlane(pl[0]);
    if ((e0 & 0xFFFF) == 0xFFFF) return;  // all-sentinel group
    const int e1 = __builtin_amdgcn_readfirstlane(pl[1]);
    const int e2 = __builtin_amdgcn_readfirstlane(pl[2]);
    const int e3 = __builtin_amdgcn_readfirstlane(pl[3]);

    const int q0 = e0 & 0xFFFF;
    const int ks = (unsigned)e0 >> 16;
    const int nk = (unsigned)e1 >> 16;
    const int t1 = e1 & 0xFFFF, t2 = e2 & 0xFFFF, t3 = e3 & 0xFFFF;
    const bool v1 = t1 != 0xFFFF, v2 = t2 != 0xFFFF, v3 = t3 != 0xFFFF;
    const int q1 = v1 ? t1 : q0;
    const int q2 = v2 ? t2 : q0;
    const int q3 = v3 ? t3 : q0;

    float* outb = out + (size_t)bh * S_LEN * D;
    if (nk == 0) {   // empty key bucket -> zero rows
        outb[(size_t)q0 * D + lane] = 0.0f;
        if (v1) outb[(size_t)q1 * D + lane] = 0.0f;
        if (v2) outb[(size_t)q2 * D + lane] = 0.0f;
        if (v3) outb[(size_t)q3 * D + lane] = 0.0f;
        return;
    }

    const int* kl     = k_list + bh * S_LEN + ks;
    const float* Kb   = K + (size_t)bh * S_LEN * D;
    const float* Vb   = V + (size_t)bh * S_LEN * D;
    const float* qr0  = Q + ((size_t)bh * S_LEN + q0) * D;   // wave-uniform: s_load
    const float* qr1  = Q + ((size_t)bh * S_LEN + q1) * D;
    const float* qr2  = Q + ((size_t)bh * S_LEN + q2) * D;
    const float* qr3  = Q + ((size_t)bh * S_LEN + q3) * D;

    float l0 = 0.f, l1 = 0.f, l2 = 0.f, l3 = 0.f;           // per-lane linear l
    float acc0 = 0.f, acc1 = 0.f, acc2 = 0.f, acc3 = 0.f;

    for (int c = 0; c * 64 < nk; ++c) {
        const int cnk  = min(64, nk - c * 64);
        const int kidx = kl[c * 64 + min(lane, cnk - 1)];   // coalesced, clamped
        const float* krow = Kb + (size_t)kidx * D;

        // ---- scores: lane = key; K-row gather shared by 4 queries
        float s0 = 0.f, s1 = 0.f, s2 = 0.f, s3 = 0.f;
#pragma unroll
        for (int d4 = 0; d4 < 16; ++d4) {
            const float4 kv = *(const float4*)(krow + d4 * 4);   // gather
            const float4 a  = *(const float4*)(qr0 + d4 * 4);    // s_load (uniform)
            const float4 b  = *(const float4*)(qr1 + d4 * 4);
            const float4 cq = *(const float4*)(qr2 + d4 * 4);
            const float4 dq = *(const float4*)(qr3 + d4 * 4);
            s0 += a.x * kv.x + a.y * kv.y + a.z * kv.z + a.w * kv.w;
            s1 += b.x * kv.x + b.y * kv.y + b.z * kv.z + b.w * kv.w;
            s2 += cq.x * kv.x + cq.y * kv.y + cq.z * kv.z + cq.w * kv.w;
            s3 += dq.x * kv.x + dq.y * kv.y + dq.z * kv.z + dq.w * kv.w;
        }

        // ---- linear no-max softmax: e = exp(s/8), per-lane l accumulation
        const bool kvalid = lane < cnk;
        const float ea = kvalid ? __expf(s0 * 0.125f) : 0.f;
        const float eb = kvalid ? __expf(s1 * 0.125f) : 0.f;
        const float ec = kvalid ? __expf(s2 * 0.125f) : 0.f;
        const float ed = kvalid ? __expf(s3 * 0.125f) : 0.f;
        l0 += ea; l1 += eb; l2 += ec; l3 += ed;
        wbuf[wv][0][lane] = ea;
        wbuf[wv][1][lane] = eb;
        wbuf[wv][2][lane] = ec;
        wbuf[wv][3][lane] = ed;
        kbuf[wv][lane]    = kidx;
        // same-wave LDS RAW: compiler inserts lgkmcnt wait

        // ---- PV: lane = dim; V rows shared by 4 queries
        const int ng = (cnk + 3) >> 2;
        for (int g = 0; g < ng; ++g) {
            const int4   kk = *(const int4*)&kbuf[wv][g * 4];
            const float4 eA = *(const float4*)&wbuf[wv][0][g * 4];
            const float4 eB = *(const float4*)&wbuf[wv][1][g * 4];
            const float4 eC = *(const float4*)&wbuf[wv][2][g * 4];
            const float4 eD = *(const float4*)&wbuf[wv][3][g * 4];
            const float vx = Vb[(size_t)kk.x * D + lane];
            const float vy = Vb[(size_t)kk.y * D + lane];
            const float vz = Vb[(size_t)kk.z * D + lane];
            const float vw = Vb[(size_t)kk.w * D + lane];
            acc0 += eA.x * vx + eA.y * vy + eA.z * vz + eA.w * vw;
            acc1 += eB.x * vx + eB.y * vy + eB.z * vz + eB.w * vw;
            acc2 += eC.x * vx + eC.y * vy + eC.z * vz + eC.w * vw;
            acc3 += eD.x * vx + eD.y * vy + eD.z * vz + eD.w * vw;
        }
    }

    // single end reduction of per-lane l (4 interleaved trees)
#pragma unroll
    for (int off = 32; off >= 1; off >>= 1) {
        l0 += __shfl_xor(l0, off, 64);
        l1 += __shfl_xor(l1, off, 64);
        l2 += __shfl_xor(l2, off, 64);
        l3 += __shfl_xor(l3, off, 64);
    }

    const float inv6 = 1.0f / 6.0f;
    outb[(size_t)q0 * D + lane] = acc0 / (l0 + 1e-8f) * inv6;
    if (v1) outb[(size_t)q1 * D + lane] = acc1 / (l1 + 1e-8f) * inv6;
    if (v2) outb[(size_t)q2 * D + lane] = acc2 / (l2 + 1e-8f) * inv6;
    if (v3) outb[(size_t)q3 * D + lane] = acc3 / (l3 + 1e-8f) * inv6;
}

extern "C" void kernel_launch(void* const* d_in, const int* in_sizes, int n_in,
                              void* d_out, int out_size, void* d_ws, size_t ws_size,
                              hipStream_t stream) {
    const float* Q   = (const float*)d_in[0];
    const float* K   = (const float*)d_in[1];
    const float* V   = (const float*)d_in[2];
    const float* rot = (const float*)d_in[3];
    float* out = (float*)d_out;

    char* ws = (char*)d_ws;
    int* q_buckets = (int*)(ws);              // 128 KB
    int* k_buckets = (int*)(ws + 131072);     // 128 KB
    int* k_list    = (int*)(ws + 262144);     // 128 KB
    int* q_plist   = (int*)(ws + 393216);     // 16*2240*4 = 140 KB

    lsh_buckets2<<<2 * BH * S_LEN / 4, 256, 0, stream>>>(Q, K, rot, q_buckets, k_buckets);
    lsh_sortfuse_bh<<<BH, 256, 0, stream>>>(q_buckets, k_buckets, q_plist, k_list);
    lsh_attn_g<<<NBLK * BH, 256, 0, stream>>>(Q, K, V, q_plist, k_list, out);
}

// Round 16
// 72.680 us; speedup vs baseline: 1.0440x; 1.0440x over previous
//
#include <hip/hip_runtime.h>
#include <math.h>

// LSH attention: B=2, H=8, S=2048, D=64, 6 bits -> 64 buckets, exact-match.
// 4 dispatches:
//  1) lsh_buckets2: bucket codes for Q and K (sign of X.rot)
//  2) lsh_sortfuse_bh: per-bh fused histogram/scan/scatter; Q-list entries
//     carry K-side bucket info inline (e0=q0|ks<<16, e1=q1|nk<<16; 0xFFFF=pad)
//  3) lsh_kpack: K rows packed in slot order, dim-block-major:
//     Ktp[bh][d4][slot][4] -> attn K reads become fully coalesced (16 lines
//     per instr instead of 64) — attacks the saturated L1/TA address pipe.
//  4) lsh_attn_p: wave per 4 same-bucket queries, low-VGPR; coalesced packed-K
//     scores; linear no-max softmax; lane=dim PV. XCD-pinned grid + coprime
//     group stride. (lsh_attn_g gather fallback if ws too small for Ktp.)

constexpr int S_LEN = 2048;
constexpr int D = 64;
constexpr int NHASH = 6;
constexpr int BH = 16;     // B*H
constexpr int NB = 64;     // 2^NHASH
constexpr int QPAD = 4;    // queries per wave
constexpr int PADQ = S_LEN + (QPAD - 1) * NB;   // 2240
constexpr int NGRP = PADQ / QPAD;               // 560 wave-groups per bh
constexpr int NBLK = NGRP / 4;                  // 140 blocks per bh (4 waves each)
constexpr int GSTRIDE = 37;                     // coprime with 140: bijective
constexpr size_t KTP_OFF = 1u << 20;            // Ktp at ws+1MB, 8MB long

// ---- Phase 1: bucket codes for Q and K in one dispatch. One wave per vector.
__global__ __launch_bounds__(256) void lsh_buckets2(const float* __restrict__ Q,
                                                    const float* __restrict__ K,
                                                    const float* __restrict__ rot,
                                                    int* __restrict__ qb,
                                                    int* __restrict__ kb) {
    const int gw   = (blockIdx.x * 256 + threadIdx.x) >> 6;
    const int lane = threadIdx.x & 63;
    const bool isK = gw >= BH * S_LEN;
    const int wid  = isK ? gw - BH * S_LEN : gw;
    const float* X = isK ? K : Q;
    int* dst       = isK ? kb : qb;
    const int h    = (wid >> 11) & 7;

    const float x  = X[(size_t)wid * D + lane];
    const float* r = rot + (size_t)h * NHASH * D + lane;
    float p0 = x * r[0 * D], p1 = x * r[1 * D], p2 = x * r[2 * D];
    float p3 = x * r[3 * D], p4 = x * r[4 * D], p5 = x * r[5 * D];
#pragma unroll
    for (int off = 32; off >= 1; off >>= 1) {
        p0 += __shfl_xor(p0, off, 64);
        p1 += __shfl_xor(p1, off, 64);
        p2 += __shfl_xor(p2, off, 64);
        p3 += __shfl_xor(p3, off, 64);
        p4 += __shfl_xor(p4, off, 64);
        p5 += __shfl_xor(p5, off, 64);
    }
    int bucket = (p0 > 0.f ? 1 : 0) | (p1 > 0.f ? 2 : 0) | (p2 > 0.f ? 4 : 0) |
                 (p3 > 0.f ? 8 : 0) | (p4 > 0.f ? 16 : 0) | (p5 > 0.f ? 32 : 0);
    if (lane == 0) dst[wid] = bucket;
}

// ---- Phase 2: fused per-bh sort. One block per bh (16 blocks x 256 threads).
__global__ __launch_bounds__(256) void lsh_sortfuse_bh(const int* __restrict__ qbuckets,
                                                       const int* __restrict__ kbuckets,
                                                       int* __restrict__ q_plist,  // [BH][PADQ]
                                                       int* __restrict__ k_list) { // [BH][S]
    __shared__ int hist[NB];
    __shared__ int cur[NB];
    __shared__ int kst[NB], kcnt[NB];
    __shared__ int qst[NB];
    __shared__ int total;
    const int bh  = blockIdx.x;
    const int tid = threadIdx.x;

    // ================= K pass =================
    if (tid < NB) hist[tid] = 0;
    __syncthreads();
    int myk[8];
#pragma unroll
    for (int i = 0; i < 8; ++i) {
        myk[i] = kbuckets[bh * S_LEN + i * 256 + tid];   // coalesced
        atomicAdd(&hist[myk[i]], 1);
    }
    __syncthreads();
    if (tid < NB) {   // wave 0: shuffle-scan the 64 bucket sizes
        const int cnt = hist[tid];
        int x = cnt;
#pragma unroll
        for (int off = 1; off < 64; off <<= 1) {
            const int y = __shfl_up(x, off, 64);
            if (tid >= off) x += y;
        }
        kst[tid]  = x - cnt;
        kcnt[tid] = cnt;
        cur[tid]  = x - cnt;
    }
    __syncthreads();
    {
        int* klp = k_list + bh * S_LEN;
#pragma unroll
        for (int i = 0; i < 8; ++i) {
            const int b    = myk[i];
            const int slot = atomicAdd(&cur[b], 1);
            klp[slot] = i * 256 + tid;
        }
    }
    __syncthreads();

    // ================= Q pass =================
    if (tid < NB) hist[tid] = 0;
    __syncthreads();
    int myq[8];
#pragma unroll
    for (int i = 0; i < 8; ++i) {
        myq[i] = qbuckets[bh * S_LEN + i * 256 + tid];
        atomicAdd(&hist[myq[i]], 1);
    }
    __syncthreads();
    if (tid < NB) {
        const int cnt = hist[tid];
        const int v   = (cnt + QPAD - 1) & ~(QPAD - 1);
        int x = v;
#pragma unroll
        for (int off = 1; off < 64; off <<= 1) {
            const int y = __shfl_up(x, off, 64);
            if (tid >= off) x += y;
        }
        qst[tid] = x - v;
        cur[tid] = x - v;
        if (tid == 63) total = x;
    }
    __syncthreads();

    int* qp = q_plist + bh * PADQ;
    // per-bucket pad sentinels (q-field 0xFFFF; keep nk in high bits for pos1)
    if (tid < NB) {
        const int cnt    = hist[tid];
        const int padded = (cnt + QPAD - 1) & ~(QPAD - 1);
        const int sent   = 0xFFFF | (kcnt[tid] << 16);
        for (int t = qst[tid] + cnt; t < qst[tid] + padded; ++t) qp[t] = sent;
    }
    for (int t = total + tid; t < PADQ; t += 256) qp[t] = -1;   // whole-group sentinel
    // scatter: entry layout depends on slot position within its group
#pragma unroll
    for (int i = 0; i < 8; ++i) {
        const int b    = myq[i];
        const int slot = atomicAdd(&cur[b], 1);
        const int pos  = slot & 3;
        int e = i * 256 + tid;
        if (pos == 0)      e |= kst[b] << 16;
        else if (pos == 1) e |= kcnt[b] << 16;
        qp[slot] = e;
    }
}

// ---- Phase 2.5: pack K into slot-ordered, dim-block-major layout.
// Ktp[bh][d4][slot][4] (floats). One wave per 4 slots; read coalesced,
// write merges into 16 x 16B segments per instruction.
__global__ __launch_bounds__(256) void lsh_kpack(const float* __restrict__ K,
                                                 const int* __restrict__ k_list,
                                                 float* __restrict__ Ktp) {
    const int gw   = (blockIdx.x * 256 + threadIdx.x) >> 6;   // [0, BH*S/4)
    const int lane = threadIdx.x & 63;
    const int bh   = gw >> 9;
    const int s0   = (gw & 511) * 4;
    const float* Kb = K + (size_t)bh * S_LEN * D;
    const int* kl   = k_list + bh * S_LEN;
    float* kt       = Ktp + (size_t)bh * 16 * S_LEN * 4;
    const int dblk  = lane >> 2, dj = lane & 3;
#pragma unroll
    for (int j = 0; j < 4; ++j) {
        const int slot = s0 + j;
        const int kidx = kl[slot];                       // wave-uniform -> s_load
        const float v  = Kb[(size_t)kidx * D + lane];    // coalesced 256B
        kt[((size_t)dblk * S_LEN + slot) * 4 + dj] = v;
    }
}

// ---- Phase 3 (packed): wave per 4 same-bucket queries, coalesced K reads.
__global__ __launch_bounds__(256) void lsh_attn_p(const float* __restrict__ Q,
                                                  const float* __restrict__ V,
                                                  const float* __restrict__ Ktp,
                                                  const int* __restrict__ q_plist,
                                                  const int* __restrict__ k_list,
                                                  float* __restrict__ out) {
    __shared__ float wbuf[4][QPAD][64];   // [wave][query][key-lane]
    __shared__ int   kbuf[4][64];

    const int wv   = threadIdx.x >> 6;
    const int lane = threadIdx.x & 63;
    const int w    = blockIdx.x;
    const int bh   = (w & 7) + 8 * ((w >> 3) & 1);   // XCD w&7 serves bh, bh+8
    const int gb   = ((w >> 4) * GSTRIDE) % NBLK;    // strided tail-balance
    const int grp  = gb * 4 + wv;                    // 4 consecutive groups/block

    const int* pl = q_plist + bh * PADQ + 4 * grp;
    const int e0 = __builtin_amdgcn_readfirstlane(pl[0]);
    if ((e0 & 0xFFFF) == 0xFFFF) return;  // all-sentinel group
    const int e1 = __builtin_amdgcn_readfirstlane(pl[1]);
    const int e2 = __builtin_amdgcn_readfirstlane(pl[2]);
    const int e3 = __builtin_amdgcn_readfirstlane(pl[3]);

    const int q0 = e0 & 0xFFFF;
    const int ks = (unsigned)e0 >> 16;
    const int nk = (unsigned)e1 >> 16;
    const int t1 = e1 & 0xFFFF, t2 = e2 & 0xFFFF, t3 = e3 & 0xFFFF;
    const bool v1 = t1 != 0xFFFF, v2 = t2 != 0xFFFF, v3 = t3 != 0xFFFF;
    const int q1 = v1 ? t1 : q0;
    const int q2 = v2 ? t2 : q0;
    const int q3 = v3 ? t3 : q0;

    float* outb = out + (size_t)bh * S_LEN * D;
    if (nk == 0) {   // empty key bucket -> zero rows
        outb[(size_t)q0 * D + lane] = 0.0f;
        if (v1) outb[(size_t)q1 * D + lane] = 0.0f;
        if (v2) outb[(size_t)q2 * D + lane] = 0.0f;
        if (v3) outb[(size_t)q3 * D + lane] = 0.0f;
        return;
    }

    const int* kl     = k_list + bh * S_LEN + ks;
    const float* ktb  = Ktp + (size_t)bh * 16 * S_LEN * 4;
    const float* Vb   = V + (size_t)bh * S_LEN * D;
    const float* qr0  = Q + ((size_t)bh * S_LEN + q0) * D;   // wave-uniform: s_load
    const float* qr1  = Q + ((size_t)bh * S_LEN + q1) * D;
    const float* qr2  = Q + ((size_t)bh * S_LEN + q2) * D;
    const float* qr3  = Q + ((size_t)bh * S_LEN + q3) * D;

    float l0 = 0.f, l1 = 0.f, l2 = 0.f, l3 = 0.f;           // per-lane linear l
    float acc0 = 0.f, acc1 = 0.f, acc2 = 0.f, acc3 = 0.f;

    for (int c = 0; c * 64 < nk; ++c) {
        const int cnk  = min(64, nk - c * 64);
        const int cl   = min(lane, cnk - 1);
        const int kidx = kl[c * 64 + cl];                   // coalesced, clamped
        const int slot = ks + c * 64 + cl;                  // packed-K slot

        // ---- scores: lane = key; coalesced packed-K reads (16 lines/instr)
        float s0 = 0.f, s1 = 0.f, s2 = 0.f, s3 = 0.f;
#pragma unroll
        for (int d4 = 0; d4 < 16; ++d4) {
            const float4 kv = *(const float4*)(ktb + ((size_t)d4 * S_LEN + slot) * 4);
            const float4 a  = *(const float4*)(qr0 + d4 * 4);    // s_load (uniform)
            const float4 b  = *(const float4*)(qr1 + d4 * 4);
            const float4 cq = *(const float4*)(qr2 + d4 * 4);
            const float4 dq = *(const float4*)(qr3 + d4 * 4);
            s0 += a.x * kv.x + a.y * kv.y + a.z * kv.z + a.w * kv.w;
            s1 += b.x * kv.x + b.y * kv.y + b.z * kv.z + b.w * kv.w;
            s2 += cq.x * kv.x + cq.y * kv.y + cq.z * kv.z + cq.w * kv.w;
            s3 += dq.x * kv.x + dq.y * kv.y + dq.z * kv.z + dq.w * kv.w;
        }

        // ---- linear no-max softmax: e = exp(s/8), per-lane l accumulation
        const bool kvalid = lane < cnk;
        const float ea = kvalid ? __expf(s0 * 0.125f) : 0.f;
        const float eb = kvalid ? __expf(s1 * 0.125f) : 0.f;
        const float ec = kvalid ? __expf(s2 * 0.125f) : 0.f;
        const float ed = kvalid ? __expf(s3 * 0.125f) : 0.f;
        l0 += ea; l1 += eb; l2 += ec; l3 += ed;
        wbuf[wv][0][lane] = ea;
        wbuf[wv][1][lane] = eb;
        wbuf[wv][2][lane] = ec;
        wbuf[wv][3][lane] = ed;
        kbuf[wv][lane]    = kidx;
        // same-wave LDS RAW: compiler inserts lgkmcnt wait

        // ---- PV: lane = dim; V rows shared by 4 queries
        const int ng = (cnk + 3) >> 2;
        for (int g = 0; g < ng; ++g) {
            const int4   kk = *(const int4*)&kbuf[wv][g * 4];
            const float4 eA = *(const float4*)&wbuf[wv][0][g * 4];
            const float4 eB = *(const float4*)&wbuf[wv][1][g * 4];
            const float4 eC = *(const float4*)&wbuf[wv][2][g * 4];
            const float4 eD = *(const float4*)&wbuf[wv][3][g * 4];
            const float vx = Vb[(size_t)kk.x * D + lane];
            const float vy = Vb[(size_t)kk.y * D + lane];
            const float vz = Vb[(size_t)kk.z * D + lane];
            const float vw = Vb[(size_t)kk.w * D + lane];
            acc0 += eA.x * vx + eA.y * vy + eA.z * vz + eA.w * vw;
            acc1 += eB.x * vx + eB.y * vy + eB.z * vz + eB.w * vw;
            acc2 += eC.x * vx + eC.y * vy + eC.z * vz + eC.w * vw;
            acc3 += eD.x * vx + eD.y * vy + eD.z * vz + eD.w * vw;
        }
    }

    // single end reduction of per-lane l (4 interleaved trees)
#pragma unroll
    for (int off = 32; off >= 1; off >>= 1) {
        l0 += __shfl_xor(l0, off, 64);
        l1 += __shfl_xor(l1, off, 64);
        l2 += __shfl_xor(l2, off, 64);
        l3 += __shfl_xor(l3, off, 64);
    }

    const float inv6 = 1.0f / 6.0f;
    outb[(size_t)q0 * D + lane] = acc0 / (l0 + 1e-8f) * inv6;
    if (v1) outb[(size_t)q1 * D + lane] = acc1 / (l1 + 1e-8f) * inv6;
    if (v2) outb[(size_t)q2 * D + lane] = acc2 / (l2 + 1e-8f) * inv6;
    if (v3) outb[(size_t)q3 * D + lane] = acc3 / (l3 + 1e-8f) * inv6;
}

// ---- Phase 3 (fallback, gather K): identical to R15 kernel.
__global__ __launch_bounds__(256) void lsh_attn_g(const float* __restrict__ Q,
                                                  const float* __restrict__ K,
                                                  const float* __restrict__ V,
                                                  const int* __restrict__ q_plist,
                                                  const int* __restrict__ k_list,
                                                  float* __restrict__ out) {
    __shared__ float wbuf[4][QPAD][64];
    __shared__ int   kbuf[4][64];

    const int wv   = threadIdx.x >> 6;
    const int lane = threadIdx.x & 63;
    const int w    = blockIdx.x;
    const int bh   = (w & 7) + 8 * ((w >> 3) & 1);
    const int gb   = ((w >> 4) * GSTRIDE) % NBLK;
    const int grp  = gb * 4 + wv;

    const int* pl = q_plist + bh * PADQ + 4 * grp;
    const int e0 = __builtin_amdgcn_readfirstlane(pl[0]);
    if ((e0 & 0xFFFF) == 0xFFFF) return;
    const int e1 = __builtin_amdgcn_readfirstlane(pl[1]);
    const int e2 = __builtin_amdgcn_readfirstlane(pl[2]);
    const int e3 = __builtin_amdgcn_readfirstlane(pl[3]);

    const int q0 = e0 & 0xFFFF;
    const int ks = (unsigned)e0 >> 16;
    const int nk = (unsigned)e1 >> 16;
    const int t1 = e1 & 0xFFFF, t2 = e2 & 0xFFFF, t3 = e3 & 0xFFFF;
    const bool v1 = t1 != 0xFFFF, v2 = t2 != 0xFFFF, v3 = t3 != 0xFFFF;
    const int q1 = v1 ? t1 : q0;
    const int q2 = v2 ? t2 : q0;
    const int q3 = v3 ? t3 : q0;

    float* outb = out + (size_t)bh * S_LEN * D;
    if (nk == 0) {
        outb[(size_t)q0 * D + lane] = 0.0f;
        if (v1) outb[(size_t)q1 * D + lane] = 0.0f;
        if (v2) outb[(size_t)q2 * D + lane] = 0.0f;
        if (v3) outb[(size_t)q3 * D + lane] = 0.0f;
        return;
    }

    const int* kl     = k_list + bh * S_LEN + ks;
    const float* Kb   = K + (size_t)bh * S_LEN * D;
    const float* Vb   = V + (size_t)bh * S_LEN * D;
    const float* qr0  = Q + ((size_t)bh * S_LEN + q0) * D;
    const float* qr1  = Q + ((size_t)bh * S_LEN + q1) * D;
    const float* qr2  = Q + ((size_t)bh * S_LEN + q2) * D;
    const float* qr3  = Q + ((size_t)bh * S_LEN + q3) * D;

    float l0 = 0.f, l1 = 0.f, l2 = 0.f, l3 = 0.f;
    float acc0 = 0.f, acc1 = 0.f, acc2 = 0.f, acc3 = 0.f;

    for (int c = 0; c * 64 < nk; ++c) {
        const int cnk  = min(64, nk - c * 64);
        const int kidx = kl[c * 64 + min(lane, cnk - 1)];
        const float* krow = Kb + (size_t)kidx * D;

        float s0 = 0.f, s1 = 0.f, s2 = 0.f, s3 = 0.f;
#pragma unroll
        for (int d4 = 0; d4 < 16; ++d4) {
            const float4 kv = *(const float4*)(krow + d4 * 4);
            const float4 a  = *(const float4*)(qr0 + d4 * 4);
            const float4 b  = *(const float4*)(qr1 + d4 * 4);
            const float4 cq = *(const float4*)(qr2 + d4 * 4);
            const float4 dq = *(const float4*)(qr3 + d4 * 4);
            s0 += a.x * kv.x + a.y * kv.y + a.z * kv.z + a.w * kv.w;
            s1 += b.x * kv.x + b.y * kv.y + b.z * kv.z + b.w * kv.w;
            s2 += cq.x * kv.x + cq.y * kv.y + cq.z * kv.z + cq.w * kv.w;
            s3 += dq.x * kv.x + dq.y * kv.y + dq.z * kv.z + dq.w * kv.w;
        }

        const bool kvalid = lane < cnk;
        const float ea = kvalid ? __expf(s0 * 0.125f) : 0.f;
        const float eb = kvalid ? __expf(s1 * 0.125f) : 0.f;
        const float ec = kvalid ? __expf(s2 * 0.125f) : 0.f;
        const float ed = kvalid ? __expf(s3 * 0.125f) : 0.f;
        l0 += ea; l1 += eb; l2 += ec; l3 += ed;
        wbuf[wv][0][lane] = ea;
        wbuf[wv][1][lane] = eb;
        wbuf[wv][2][lane] = ec;
        wbuf[wv][3][lane] = ed;
        kbuf[wv][lane]    = kidx;

        const int ng = (cnk + 3) >> 2;
        for (int g = 0; g < ng; ++g) {
            const int4   kk = *(const int4*)&kbuf[wv][g * 4];
            const float4 eA = *(const float4*)&wbuf[wv][0][g * 4];
            const float4 eB = *(const float4*)&wbuf[wv][1][g * 4];
            const float4 eC = *(const float4*)&wbuf[wv][2][g * 4];
            const float4 eD = *(const float4*)&wbuf[wv][3][g * 4];
            const float vx = Vb[(size_t)kk.x * D + lane];
            const float vy = Vb[(size_t)kk.y * D + lane];
            const float vz = Vb[(size_t)kk.z * D + lane];
            const float vw = Vb[(size_t)kk.w * D + lane];
            acc0 += eA.x * vx + eA.y * vy + eA.z * vz + eA.w * vw;
            acc1 += eB.x * vx + eB.y * vy + eB.z * vz + eB.w * vw;
            acc2 += eC.x * vx + eC.y * vy + eC.z * vz + eC.w * vw;
            acc3 += eD.x * vx + eD.y * vy + eD.z * vz + eD.w * vw;
        }
    }

#pragma unroll
    for (int off = 32; off >= 1; off >>= 1) {
        l0 += __shfl_xor(l0, off, 64);
        l1 += __shfl_xor(l1, off, 64);
        l2 += __shfl_xor(l2, off, 64);
        l3 += __shfl_xor(l3, off, 64);
    }

    const float inv6 = 1.0f / 6.0f;
    outb[(size_t)q0 * D + lane] = acc0 / (l0 + 1e-8f) * inv6;
    if (v1) outb[(size_t)q1 * D + lane] = acc1 / (l1 + 1e-8f) * inv6;
    if (v2) outb[(size_t)q2 * D + lane] = acc2 / (l2 + 1e-8f) * inv6;
    if (v3) outb[(size_t)q3 * D + lane] = acc3 / (l3 + 1e-8f) * inv6;
}

extern "C" void kernel_launch(void* const* d_in, const int* in_sizes, int n_in,
                              void* d_out, int out_size, void* d_ws, size_t ws_size,
                              hipStream_t stream) {
    const float* Q   = (const float*)d_in[0];
    const float* K   = (const float*)d_in[1];
    const float* V   = (const float*)d_in[2];
    const float* rot = (const float*)d_in[3];
    float* out = (float*)d_out;

    char* ws = (char*)d_ws;
    int* q_buckets = (int*)(ws);              // 128 KB
    int* k_buckets = (int*)(ws + 131072);     // 128 KB
    int* k_list    = (int*)(ws + 262144);     // 128 KB
    int* q_plist   = (int*)(ws + 393216);     // 16*2240*4 = 140 KB
    float* Ktp     = (float*)(ws + KTP_OFF);  // 16*16*2048*4*4B = 8 MB

    const size_t ktp_bytes = (size_t)BH * 16 * S_LEN * 4 * sizeof(float);
    const bool packed = ws_size >= KTP_OFF + ktp_bytes;

    lsh_buckets2<<<2 * BH * S_LEN / 4, 256, 0, stream>>>(Q, K, rot, q_buckets, k_buckets);
    lsh_sortfuse_bh<<<BH, 256, 0, stream>>>(q_buckets, k_buckets, q_plist, k_list);
    if (packed) {
        lsh_kpack<<<BH * S_LEN / 16, 256, 0, stream>>>(K, k_list, Ktp);
        lsh_attn_p<<<NBLK * BH, 256, 0, stream>>>(Q, V, Ktp, q_plist, k_list, out);
    } else {
        lsh_attn_g<<<NBLK * BH, 256, 0, stream>>>(Q, K, V, q_plist, k_list, out);
    }
}